// Round 12
// baseline (334.879 us; speedup 1.0000x reference)
//
#include <hip/hip_runtime.h>
#include <stdint.h>

#define E 128
#define W 64
#define C 1024
#define S 8
#define NBUCK 4096

typedef unsigned long long u64;
typedef unsigned int u32;

__device__ __forceinline__ float sigm(float x) { return 1.0f / (1.0f + expf(-x)); }

// Wave-level suffix-scan threshold finder over hist[4096]. 1024 threads,
// 4 buckets/thread, 3 barriers.
__device__ __forceinline__ int suffix_threshold(u32* hist, u32* wtot, int* s_B,
                                                int t, int lane, int wid) {
  const int b0 = t << 2;
  const u32 v0 = hist[b0], v1 = hist[b0 + 1], v2 = hist[b0 + 2], v3 = hist[b0 + 3];
  const u32 s3 = v3, s2 = v2 + s3, s1 = v1 + s2, s0 = v0 + s1;
  u32 incl = s0;
#pragma unroll
  for (int off = 1; off < 64; off <<= 1) {
    const u32 n = __shfl_down(incl, off, 64);
    if (lane + off < 64) incl += n;
  }
  if (lane == 0) wtot[wid] = incl;
  __syncthreads();
  u32 wsuf = 0;
  for (int i = wid + 1; i < 16; ++i) wsuf += wtot[i];
  const u32 above = wsuf + (incl - s0);
  hist[b0]     = above + s0;
  hist[b0 + 1] = above + s1;
  hist[b0 + 2] = above + s2;
  hist[b0 + 3] = above + s3;
  __syncthreads();
#pragma unroll
  for (int j = 0; j < 4; ++j) {
    const int b = b0 + j;
    const u32 here = hist[b];
    const u32 nxt = (b + 1 < NBUCK) ? hist[b + 1] : 0u;
    if (here >= 64u && nxt < 64u) *s_B = b;
  }
  __syncthreads();
  return *s_B;
}

// ---------------------------------------------------------------------------
// kA: per-beam serial chain (rank -> gather -> LSTM -> M1). grid = 64 x 1024.
//   Sheds M2 (moved to kB); writes hmid[w][384].
// ---------------------------------------------------------------------------
__global__ __launch_bounds__(1024) void kA(
    int step,
    const float* __restrict__ ent_emb, const float* __restrict__ rel_emb,
    const float* __restrict__ relation,
    const float* __restrict__ W1, const float* __restrict__ b1,
    const float* __restrict__ lstm_k, const float* __restrict__ lstm_r,
    const float* __restrict__ lstm_b,
    const int* __restrict__ cand_rel_ids, const int* __restrict__ cand_ent_ids,
    const int* __restrict__ start_ent,
    float* __restrict__ Hst, float* __restrict__ Cst,   // each [2][W][E]
    float* __restrict__ rconstb,                         // [384]
    const u64* __restrict__ rowtop,                      // [W][64]
    float* __restrict__ hmidb)                           // [W][384]
{
  const int w = blockIdx.x, t = threadIdx.x;
  const int lane = t & 63, wid = t >> 6;
  __shared__ __align__(16) float xin[384];
  __shared__ __align__(16) float xcat2[256];   // [ent_emb[cur], hnew]
  __shared__ __align__(16) float z[512];       // lstm z; rconst at step 0
  __shared__ u32 wtot[16];
  __shared__ int s_par, s_rid, s_eid, s_cnt, s_B;
  __shared__ __align__(16) unsigned char arena[32768];
  u32* hist = (u32*)arena;
  u64* coll = (u64*)arena;
  float4* zacc = (float4*)arena;

  float* Hn = Hst + (size_t)(step & 1) * W * E;
  float* Cn = Cst + (size_t)(step & 1) * W * E;
  const float* Hp = Hst + (size_t)((step + 1) & 1) * W * E;
  const float* Cp = Cst + (size_t)((step + 1) & 1) * W * E;

  if (step == 0) {
    // ---- init + rconst = relation @ W1[256:384,:] -------------------------
    const int cur = start_ent[w];
    if (t < 128) {
      xcat2[t] = ent_emb[(size_t)cur * E + t];
      xcat2[128 + t] = 0.f;
      Hn[w * E + t] = 0.f;
      Cn[w * E + t] = 0.f;
    }
    if (t < 384) {
      const int jg = t % 96, ks = t / 96;       // 4 slices x 32 rows
      const int j0 = jg << 2, k0 = ks << 5;
      float4 acc = make_float4(0.f, 0.f, 0.f, 0.f);
#pragma unroll 8
      for (int kk = 0; kk < 32; ++kk) {
        const int k = k0 + kk;
        const float4 wt = *(const float4*)(W1 + (size_t)(256 + k) * 384 + j0);
        const float xk = relation[k];
        acc.x += xk * wt.x; acc.y += xk * wt.y;
        acc.z += xk * wt.z; acc.w += xk * wt.w;
      }
      zacc[t] = acc;
    }
    __syncthreads();
    if (t < 96) {
      float4 a = zacc[t];
#pragma unroll
      for (int sl = 1; sl < 4; ++sl) {
        const float4 bq = zacc[sl * 96 + t];
        a.x += bq.x; a.y += bq.y; a.z += bq.z; a.w += bq.w;
      }
      ((float4*)z)[t] = a;
      *(float4*)(rconstb + (t << 2)) = a;
    }
    __syncthreads();
  } else {
    // ---- R: rank rowtop, keep rank w --------------------------------------
    if (t == 0) s_cnt = 0;
    ((uint4*)hist)[t] = make_uint4(0u, 0u, 0u, 0u);
    __syncthreads();
    u64 myk[4];
#pragma unroll
    for (int j = 0; j < 4; ++j) {
      myk[j] = rowtop[t + (j << 10)];
      atomicAdd(&hist[(u32)(myk[j] >> 51) & 0xFFFu], 1u);
    }
    __syncthreads();
    const int B = suffix_threshold(hist, wtot, &s_B, t, lane, wid);
#pragma unroll
    for (int j = 0; j < 4; ++j)
      if ((int)((myk[j] >> 51) & 0xFFFull) >= B) coll[atomicAdd(&s_cnt, 1)] = myk[j];
    __syncthreads();
    const int M = s_cnt;
    for (int i = t; i < M; i += 1024) {
      const u64 ki = coll[i];
      int r = 0;
      for (int j = 0; j < M; ++j) r += (coll[j] > ki);
      if (r == w) {
        const u32 flat = ~(u32)(ki & 0xFFFFFFFFull);
        const int p = (int)(flat >> 10);
        const int sl = (int)(flat & 1023u);
        const size_t cbase = (size_t)(step - 1) * W * C + (size_t)p * C + sl;
        s_par = p;
        s_rid = cand_rel_ids[cbase];
        s_eid = cand_ent_ids[cbase];
      }
    }
    __syncthreads();
    const int par = s_par, rid = s_rid, eid = s_eid;
    // ---- G: gather --------------------------------------------------------
    if (t < 384) {
      float v;
      if (t < 128) v = rel_emb[(size_t)rid * E + t];
      else if (t < 256) v = ent_emb[(size_t)eid * E + (t - 128)];
      else v = Hp[(size_t)par * E + (t - 256)];
      xin[t] = v;
    } else if (t < 512) {
      xcat2[t - 384] = ent_emb[(size_t)eid * E + (t - 384)];
    }
    __syncthreads();
    // ---- Z: z = xin @ [K;R] + b, 8 k-slices x 48 rows, f4 cols ------------
    {
      const int ks = t >> 7, jg = t & 127;
      const int j0 = jg << 2, k0 = ks * 48;
      float4 acc = make_float4(0.f, 0.f, 0.f, 0.f);
#pragma unroll 8
      for (int kk = 0; kk < 48; ++kk) {
        const int k = k0 + kk;
        const float* Wp = (k < 256) ? (lstm_k + (size_t)k * 512 + j0)
                                    : (lstm_r + (size_t)(k - 256) * 512 + j0);
        const float4 wt = *(const float4*)Wp;
        const float xk = xin[k];
        acc.x += xk * wt.x; acc.y += xk * wt.y;
        acc.z += xk * wt.z; acc.w += xk * wt.w;
      }
      zacc[t] = acc;
    }
    __syncthreads();
    if (t < 128) {
      float4 a = zacc[t];
#pragma unroll
      for (int sl = 1; sl < 8; ++sl) {
        const float4 bq = zacc[sl * 128 + t];
        a.x += bq.x; a.y += bq.y; a.z += bq.z; a.w += bq.w;
      }
      const float4 bb = *(const float4*)(lstm_b + (t << 2));
      a.x += bb.x; a.y += bb.y; a.z += bb.z; a.w += bb.w;
      ((float4*)z)[t] = a;
    }
    __syncthreads();
    if (t < 128) {
      const float zi = z[t], zf = z[128 + t], zg = z[256 + t], zo = z[384 + t];
      const float cp = Cp[(size_t)par * E + t];
      const float cn = sigm(zf) * cp + sigm(zi) * tanhf(zg);
      const float hn = sigm(zo) * tanhf(cn);
      xcat2[128 + t] = hn;
      Hn[w * E + t] = hn;
      Cn[w * E + t] = cn;
    }
    __syncthreads();
  }

  // ---- M1: hmid = relu(xcat2 @ W1[0:256,:] + rconst + b1) -> hmidb ---------
  if (t < 768) {
    const int jg = t % 96, ks = t / 96;          // 8 slices x 32 rows
    const int j0 = jg << 2, k0 = ks << 5;
    float4 acc = make_float4(0.f, 0.f, 0.f, 0.f);
#pragma unroll 8
    for (int kk = 0; kk < 32; ++kk) {
      const int k = k0 + kk;
      const float4 wt = *(const float4*)(W1 + (size_t)k * 384 + j0);
      const float xk = xcat2[k];
      acc.x += xk * wt.x; acc.y += xk * wt.y;
      acc.z += xk * wt.z; acc.w += xk * wt.w;
    }
    zacc[t] = acc;
  }
  __syncthreads();
  if (t < 96) {
    float4 a = zacc[t];
#pragma unroll
    for (int sl = 1; sl < 8; ++sl) {
      const float4 bq = zacc[sl * 96 + t];
      a.x += bq.x; a.y += bq.y; a.z += bq.z; a.w += bq.w;
    }
    const float4 rc = (step == 0) ? ((const float4*)z)[t]
                                  : *(const float4*)(rconstb + (t << 2));
    const float4 bb = *(const float4*)(b1 + (t << 2));
    float4 hv;
    hv.x = fmaxf(a.x + rc.x + bb.x, 0.f);
    hv.y = fmaxf(a.y + rc.y + bb.y, 0.f);
    hv.z = fmaxf(a.z + rc.z + bb.z, 0.f);
    hv.w = fmaxf(a.w + rc.w + bb.w, 0.f);
    *(float4*)(hmidb + (size_t)w * 384 + (t << 2)) = hv;
  }
}

// ---------------------------------------------------------------------------
// kB: M2 col-slice + partial scoring. grid = 256 (= beam x 4 dim-slices) x 1024.
//   Block (w,q): feat[64q..64q+64) = relu(hmid @ W2[:,64q:..] + b2[..]),
//   then partial score over those 64 dims for all 1024 candidates.
// ---------------------------------------------------------------------------
__global__ __launch_bounds__(1024) void kB(
    int step,
    const float* __restrict__ ent_emb, const float* __restrict__ rel_emb,
    const float* __restrict__ W2, const float* __restrict__ b2,
    const int* __restrict__ cand_rel_ids, const int* __restrict__ cand_ent_ids,
    const float* __restrict__ hmidb, float* __restrict__ scores4)
{
  const int b = blockIdx.x, t = threadIdx.x;
  const int w = b >> 2, q = b & 3;
  __shared__ __align__(16) float hmidl[384];
  __shared__ __align__(16) float zred[1024];
  __shared__ __align__(16) float feats[64];

  // prefetch candidate ids (independent of M2 phase)
  const size_t sbase = (size_t)step * W * C + (size_t)w * C + t;
  const int rid = cand_rel_ids[sbase];
  const int eid = cand_ent_ids[sbase];

  if (t < 384) hmidl[t] = hmidb[(size_t)w * 384 + t];
  __syncthreads();

  // M2 slice: output o = t&63 (col 64q+o), 16 k-slices x 24 rows
  {
    const int o = t & 63, ks = t >> 6;
    const int col = (q << 6) + o, k0 = ks * 24;
    float a0 = 0.f, a1 = 0.f, a2 = 0.f, a3 = 0.f;
#pragma unroll 6
    for (int kk = 0; kk < 24; kk += 4) {
      const int k = k0 + kk;
      a0 += hmidl[k]     * W2[(size_t)(k)     * 256 + col];
      a1 += hmidl[k + 1] * W2[(size_t)(k + 1) * 256 + col];
      a2 += hmidl[k + 2] * W2[(size_t)(k + 2) * 256 + col];
      a3 += hmidl[k + 3] * W2[(size_t)(k + 3) * 256 + col];
    }
    zred[t] = (a0 + a1) + (a2 + a3);
  }
  __syncthreads();
  if (t < 64) {
    float a = 0.f;
#pragma unroll
    for (int sl = 0; sl < 16; ++sl) a += zred[(sl << 6) + t];
    feats[t] = fmaxf(a + b2[(q << 6) + t], 0.f);
  }
  __syncthreads();

  // partial score for candidate t over dims [64q, 64q+64)
  {
    const float4* row = (q < 2)
        ? (const float4*)(rel_emb + (size_t)rid * E + (q << 6))
        : (const float4*)(ent_emb + (size_t)eid * E + ((q - 2) << 6));
    const float4* f4 = (const float4*)feats;
    float ax = 0.f, ay = 0.f, az = 0.f, aw = 0.f;
#pragma unroll
    for (int i = 0; i < 16; ++i) {
      const float4 r = row[i], f = f4[i];
      ax += r.x * f.x; ay += r.y * f.y; az += r.z * f.z; aw += r.w * f.w;
    }
    scores4[((size_t)q * W + w) * C + t] = (ax + ay) + (az + aw);
  }
}

// ---------------------------------------------------------------------------
// kC: sum 4 partials -> softmax -> out, per-row top-64 -> rowtop. 64 x 1024.
// ---------------------------------------------------------------------------
__global__ __launch_bounds__(1024) void kC(
    int step, int last, const float* __restrict__ scores4,
    float* __restrict__ out, u64* __restrict__ rowtop)
{
  const int w = blockIdx.x, t = threadIdx.x;
  const int lane = t & 63, wid = t >> 6;
  __shared__ float sred[16];
  __shared__ float s_m, s_inv;
  __shared__ u32 wtot[16];
  __shared__ int s_cnt, s_B;
  __shared__ __align__(16) unsigned char arena[32768];
  u32* hist = (u32*)arena;
  u64* coll = (u64*)arena;

  const float p0 = scores4[((size_t)0 * W + w) * C + t];
  const float p1 = scores4[((size_t)1 * W + w) * C + t];
  const float p2 = scores4[((size_t)2 * W + w) * C + t];
  const float p3 = scores4[((size_t)3 * W + w) * C + t];
  const float score = (p0 + p1) + (p2 + p3);

  float v = score;
#pragma unroll
  for (int d = 32; d; d >>= 1) v = fmaxf(v, __shfl_xor(v, d, 64));
  if (lane == 0) sred[wid] = v;
  __syncthreads();
  if (t == 0) {
    float mm = sred[0];
#pragma unroll
    for (int i = 1; i < 16; ++i) mm = fmaxf(mm, sred[i]);
    s_m = mm;
  }
  __syncthreads();
  const float pexp = expf(score - s_m);
  v = pexp;
#pragma unroll
  for (int d = 32; d; d >>= 1) v += __shfl_xor(v, d, 64);
  if (lane == 0) sred[wid] = v;
  __syncthreads();
  if (t == 0) {
    float ss = sred[0];
#pragma unroll
    for (int i = 1; i < 16; ++i) ss += sred[i];
    s_inv = 1.f / ss;
  }
  __syncthreads();
  const float prob = pexp * s_inv;
  out[(size_t)step * W * C + (size_t)w * C + t] = prob;

  if (!last) {
    ((uint4*)hist)[t] = make_uint4(0u, 0u, 0u, 0u);
    if (t == 0) s_cnt = 0;
    __syncthreads();
    const u32 mono = __float_as_uint(prob) | 0x80000000u;
    const u64 key = ((u64)mono << 32) | (u32)~(u32)(w * C + t);
    atomicAdd(&hist[(mono >> 19) & 0xFFFu], 1u);
    __syncthreads();
    const int B = suffix_threshold(hist, wtot, &s_B, t, lane, wid);
    if ((int)((mono >> 19) & 0xFFFu) >= B) coll[atomicAdd(&s_cnt, 1)] = key;
    __syncthreads();
    const int M = s_cnt;
    for (int i = t; i < M; i += 1024) {
      const u64 ki = coll[i];
      int r = 0;
      for (int j = 0; j < M; ++j) r += (coll[j] > ki);
      if (r < 64) rowtop[(size_t)w * 64 + r] = ki;
    }
  }
}

// ---------------------------------------------------------------------------
extern "C" void kernel_launch(void* const* d_in, const int* in_sizes, int n_in,
                              void* d_out, int out_size, void* d_ws, size_t ws_size,
                              hipStream_t stream) {
  const float* ent_emb  = (const float*)d_in[0];
  const float* rel_emb  = (const float*)d_in[1];
  const float* relation = (const float*)d_in[2];
  const float* W1 = (const float*)d_in[3];
  const float* b1 = (const float*)d_in[4];
  const float* W2 = (const float*)d_in[5];
  const float* b2 = (const float*)d_in[6];
  const float* lstm_k = (const float*)d_in[7];
  const float* lstm_r = (const float*)d_in[8];
  const float* lstm_b = (const float*)d_in[9];
  const int* cr = (const int*)d_in[10];
  const int* ce = (const int*)d_in[11];
  const int* start_ent = (const int*)d_in[12];
  float* out = (float*)d_out;

  u64* rowtop = (u64*)d_ws;                                 // W*64 u64
  float* Hst = (float*)(rowtop + (size_t)W * 64);           // 2*W*E
  float* Cst = Hst + (size_t)2 * W * E;                     // 2*W*E
  float* rconstb = Cst + (size_t)2 * W * E;                 // 384
  float* hmidb = rconstb + 384;                             // W*384
  float* scores4 = hmidb + (size_t)W * 384;                 // 4*W*C

  for (int s = 0; s < S; ++s) {
    kA<<<W, 1024, 0, stream>>>(s, ent_emb, rel_emb, relation, W1, b1,
                               lstm_k, lstm_r, lstm_b, cr, ce, start_ent,
                               Hst, Cst, rconstb, rowtop, hmidb);
    kB<<<W * 4, 1024, 0, stream>>>(s, ent_emb, rel_emb, W2, b2, cr, ce,
                                   hmidb, scores4);
    kC<<<W, 1024, 0, stream>>>(s, (s == S - 1) ? 1 : 0, scores4, out, rowtop);
  }
}

// Round 13
// 286.025 us; speedup vs baseline: 1.1708x; 1.1708x over previous
//
#include <hip/hip_runtime.h>
#include <stdint.h>

#define E 128
#define W 64
#define C 1024
#define S 8
#define NBUCK 4096

typedef unsigned long long u64;
typedef unsigned int u32;

__device__ __forceinline__ float sigm(float x) { return 1.0f / (1.0f + expf(-x)); }

// Wave-level suffix-scan threshold finder over hist[4096]. 1024 threads,
// 4 buckets/thread, 3 barriers.
__device__ __forceinline__ int suffix_threshold(u32* hist, u32* wtot, int* s_B,
                                                int t, int lane, int wid) {
  const int b0 = t << 2;
  const u32 v0 = hist[b0], v1 = hist[b0 + 1], v2 = hist[b0 + 2], v3 = hist[b0 + 3];
  const u32 s3 = v3, s2 = v2 + s3, s1 = v1 + s2, s0 = v0 + s1;
  u32 incl = s0;
#pragma unroll
  for (int off = 1; off < 64; off <<= 1) {
    const u32 n = __shfl_down(incl, off, 64);
    if (lane + off < 64) incl += n;
  }
  if (lane == 0) wtot[wid] = incl;
  __syncthreads();
  u32 wsuf = 0;
  for (int i = wid + 1; i < 16; ++i) wsuf += wtot[i];
  const u32 above = wsuf + (incl - s0);
  hist[b0]     = above + s0;
  hist[b0 + 1] = above + s1;
  hist[b0 + 2] = above + s2;
  hist[b0 + 3] = above + s3;
  __syncthreads();
#pragma unroll
  for (int j = 0; j < 4; ++j) {
    const int b = b0 + j;
    const u32 here = hist[b];
    const u32 nxt = (b + 1 < NBUCK) ? hist[b + 1] : 0u;
    if (here >= 64u && nxt < 64u) *s_B = b;
  }
  __syncthreads();
  return *s_B;
}

// ---------------------------------------------------------------------------
// kRelz: relz[r][j] = sum_k rel_emb[r][k] * lstm_k[k][j], r<1000, j<512.
// grid = 250 x 1024 (4 rels/block, thread = (col j, k-half h)). One-time.
// ---------------------------------------------------------------------------
__global__ __launch_bounds__(1024) void kRelz(
    const float* __restrict__ rel_emb, const float* __restrict__ lstm_k,
    float* __restrict__ relz)
{
  const int b = blockIdx.x, t = threadIdx.x;
  const int j = t & 511, h = t >> 9;
  __shared__ float rl[4][128];
  __shared__ float zr[1024];
  const int r0 = b << 2;
  for (int i = t; i < 4 * 128; i += 1024)
    rl[i >> 7][i & 127] = rel_emb[(size_t)(r0 + (i >> 7)) * E + (i & 127)];
  __syncthreads();
  for (int rr = 0; rr < 4; ++rr) {
    const int k0 = h << 6;
    float a0 = 0.f, a1 = 0.f, a2 = 0.f, a3 = 0.f;
#pragma unroll 4
    for (int kk = 0; kk < 64; kk += 4) {
      const int k = k0 + kk;
      a0 += rl[rr][k]     * lstm_k[(size_t)(k)     * 512 + j];
      a1 += rl[rr][k + 1] * lstm_k[(size_t)(k + 1) * 512 + j];
      a2 += rl[rr][k + 2] * lstm_k[(size_t)(k + 2) * 512 + j];
      a3 += rl[rr][k + 3] * lstm_k[(size_t)(k + 3) * 512 + j];
    }
    zr[t] = (a0 + a1) + (a2 + a3);
    __syncthreads();
    if (h == 0) relz[(size_t)(r0 + rr) * 512 + j] = zr[j] + zr[512 + j];
    __syncthreads();
  }
}

// ---------------------------------------------------------------------------
// kA: per-beam serial chain (rank -> gather -> LSTM -> M1 -> sparse M2).
// grid = 64 x 1024.
// ---------------------------------------------------------------------------
__global__ __launch_bounds__(1024) void kA(
    int step,
    const float* __restrict__ ent_emb, const float* __restrict__ rel_emb,
    const float* __restrict__ relation,
    const float* __restrict__ W1, const float* __restrict__ b1,
    const float* __restrict__ W2, const float* __restrict__ b2,
    const float* __restrict__ lstm_k, const float* __restrict__ lstm_r,
    const float* __restrict__ lstm_b, const float* __restrict__ relz,
    const int* __restrict__ cand_rel_ids, const int* __restrict__ cand_ent_ids,
    const int* __restrict__ start_ent,
    float* __restrict__ Hst, float* __restrict__ Cst,   // each [2][W][E]
    float* __restrict__ rconstb,                         // [384]
    const u64* __restrict__ rowtop,                      // [W][64]
    float* __restrict__ featb)                           // [W][256]
{
  const int w = blockIdx.x, t = threadIdx.x;
  const int lane = t & 63, wid = t >> 6;
  __shared__ __align__(16) float xin[384];
  __shared__ __align__(16) float xcat2[256];   // [ent_emb[cur], hnew]
  __shared__ __align__(16) float z[512];       // lstm z; rconst at step 0
  __shared__ __align__(16) float hmid[384];
  __shared__ u32 wtot[16];
  __shared__ int s_par, s_rid, s_eid, s_cnt, s_B;
  __shared__ int nzidx[384];
  __shared__ int woff[7];
  __shared__ __align__(16) unsigned char arena[32768];
  u32* hist = (u32*)arena;
  u64* coll = (u64*)arena;
  float4* zacc = (float4*)arena;

  float* Hn = Hst + (size_t)(step & 1) * W * E;
  float* Cn = Cst + (size_t)(step & 1) * W * E;
  const float* Hp = Hst + (size_t)((step + 1) & 1) * W * E;
  const float* Cp = Cst + (size_t)((step + 1) & 1) * W * E;

  int rid_sel = 0;
  if (step == 0) {
    // ---- init + rconst = relation @ W1[256:384,:] -------------------------
    const int cur = start_ent[w];
    if (t < 128) {
      xcat2[t] = ent_emb[(size_t)cur * E + t];
      xcat2[128 + t] = 0.f;
      Hn[w * E + t] = 0.f;
      Cn[w * E + t] = 0.f;
    }
    if (t < 384) {
      const int jg = t % 96, ks = t / 96;       // 4 slices x 32 rows
      const int j0 = jg << 2, k0 = ks << 5;
      float4 acc = make_float4(0.f, 0.f, 0.f, 0.f);
#pragma unroll 8
      for (int kk = 0; kk < 32; ++kk) {
        const int k = k0 + kk;
        const float4 wt = *(const float4*)(W1 + (size_t)(256 + k) * 384 + j0);
        const float xk = relation[k];
        acc.x += xk * wt.x; acc.y += xk * wt.y;
        acc.z += xk * wt.z; acc.w += xk * wt.w;
      }
      zacc[t] = acc;
    }
    __syncthreads();
    if (t < 96) {
      float4 a = zacc[t];
#pragma unroll
      for (int sl = 1; sl < 4; ++sl) {
        const float4 bq = zacc[sl * 96 + t];
        a.x += bq.x; a.y += bq.y; a.z += bq.z; a.w += bq.w;
      }
      ((float4*)z)[t] = a;
      *(float4*)(rconstb + (t << 2)) = a;
    }
    __syncthreads();
  } else {
    // ---- R: rank rowtop, keep rank w --------------------------------------
    if (t == 0) s_cnt = 0;
    ((uint4*)hist)[t] = make_uint4(0u, 0u, 0u, 0u);
    __syncthreads();
    u64 myk[4];
#pragma unroll
    for (int j = 0; j < 4; ++j) {
      myk[j] = rowtop[t + (j << 10)];
      atomicAdd(&hist[(u32)(myk[j] >> 51) & 0xFFFu], 1u);
    }
    __syncthreads();
    const int B = suffix_threshold(hist, wtot, &s_B, t, lane, wid);
#pragma unroll
    for (int j = 0; j < 4; ++j)
      if ((int)((myk[j] >> 51) & 0xFFFull) >= B) coll[atomicAdd(&s_cnt, 1)] = myk[j];
    __syncthreads();
    const int M = s_cnt;
    for (int i = t; i < M; i += 1024) {
      const u64 ki = coll[i];
      int r = 0;
      for (int j = 0; j < M; ++j) r += (coll[j] > ki);
      if (r == w) {
        const u32 flat = ~(u32)(ki & 0xFFFFFFFFull);
        const int p = (int)(flat >> 10);
        const int sl = (int)(flat & 1023u);
        const size_t cbase = (size_t)(step - 1) * W * C + (size_t)p * C + sl;
        s_par = p;
        s_rid = cand_rel_ids[cbase];
        s_eid = cand_ent_ids[cbase];
      }
    }
    __syncthreads();
    const int par = s_par, rid = s_rid, eid = s_eid;
    rid_sel = rid;
    // ---- G: gather (rel part of xin replaced by relz table) ---------------
    if (t >= 128 && t < 384) {
      float v;
      if (t < 256) v = ent_emb[(size_t)eid * E + (t - 128)];
      else v = Hp[(size_t)par * E + (t - 256)];
      xin[t] = v;
    } else if (t >= 384 && t < 512) {
      xcat2[t - 384] = ent_emb[(size_t)eid * E + (t - 384)];
    }
    __syncthreads();
    // ---- Z: z = relz[rid] + xin[128:384] @ [K(128:);R] + b -----------------
    {
      const int ks = t >> 7, jg = t & 127;
      const int j0 = jg << 2, k0 = 128 + (ks << 5);
      float4 acc = make_float4(0.f, 0.f, 0.f, 0.f);
#pragma unroll 8
      for (int kk = 0; kk < 32; ++kk) {
        const int k = k0 + kk;
        const float* Wp = (k < 256) ? (lstm_k + (size_t)k * 512 + j0)
                                    : (lstm_r + (size_t)(k - 256) * 512 + j0);
        const float4 wt = *(const float4*)Wp;
        const float xk = xin[k];
        acc.x += xk * wt.x; acc.y += xk * wt.y;
        acc.z += xk * wt.z; acc.w += xk * wt.w;
      }
      zacc[t] = acc;
    }
    __syncthreads();
    if (t < 128) {
      float4 a = zacc[t];
#pragma unroll
      for (int sl = 1; sl < 8; ++sl) {
        const float4 bq = zacc[sl * 128 + t];
        a.x += bq.x; a.y += bq.y; a.z += bq.z; a.w += bq.w;
      }
      const float4 rz = *(const float4*)(relz + (size_t)rid * 512 + (t << 2));
      const float4 bb = *(const float4*)(lstm_b + (t << 2));
      a.x += rz.x + bb.x; a.y += rz.y + bb.y;
      a.z += rz.z + bb.z; a.w += rz.w + bb.w;
      ((float4*)z)[t] = a;
    }
    __syncthreads();
    if (t < 128) {
      const float zi = z[t], zf = z[128 + t], zg = z[256 + t], zo = z[384 + t];
      const float cp = Cp[(size_t)par * E + t];
      const float cn = sigm(zf) * cp + sigm(zi) * tanhf(zg);
      const float hn = sigm(zo) * tanhf(cn);
      xcat2[128 + t] = hn;
      Hn[w * E + t] = hn;
      Cn[w * E + t] = cn;
    }
    __syncthreads();
  }
  (void)rid_sel;

  // ---- M1: hmid = relu(xcat2 @ W1[0:256,:] + rconst + b1) ------------------
  if (t < 768) {
    const int jg = t % 96, ks = t / 96;          // 8 slices x 32 rows
    const int j0 = jg << 2, k0 = ks << 5;
    float4 acc = make_float4(0.f, 0.f, 0.f, 0.f);
#pragma unroll 8
    for (int kk = 0; kk < 32; ++kk) {
      const int k = k0 + kk;
      const float4 wt = *(const float4*)(W1 + (size_t)k * 384 + j0);
      const float xk = xcat2[k];
      acc.x += xk * wt.x; acc.y += xk * wt.y;
      acc.z += xk * wt.z; acc.w += xk * wt.w;
    }
    zacc[t] = acc;
  }
  __syncthreads();
  if (t < 96) {
    float4 a = zacc[t];
#pragma unroll
    for (int sl = 1; sl < 8; ++sl) {
      const float4 bq = zacc[sl * 96 + t];
      a.x += bq.x; a.y += bq.y; a.z += bq.z; a.w += bq.w;
    }
    const float4 rc = (step == 0) ? ((const float4*)z)[t]
                                  : *(const float4*)(rconstb + (t << 2));
    const float4 bb = *(const float4*)(b1 + (t << 2));
    float4 hv;
    hv.x = fmaxf(a.x + rc.x + bb.x, 0.f);
    hv.y = fmaxf(a.y + rc.y + bb.y, 0.f);
    hv.z = fmaxf(a.z + rc.z + bb.z, 0.f);
    hv.w = fmaxf(a.w + rc.w + bb.w, 0.f);
    ((float4*)hmid)[t] = hv;
  }
  __syncthreads();

  // ---- nz compaction of hmid (deterministic ballot scan) -------------------
  if (t < 384) {
    const u64 mask = __ballot(hmid[t] > 0.f);
    if ((t & 63) == 0) woff[(t >> 6) + 1] = __popcll(mask);
  }
  __syncthreads();
  if (t == 0) {
    woff[0] = 0;
    for (int i = 1; i < 7; ++i) woff[i] += woff[i - 1];
  }
  __syncthreads();
  if (t < 384) {
    const u64 mask = __ballot(hmid[t] > 0.f);
    if (hmid[t] > 0.f) {
      const int pos = woff[t >> 6] +
                      (int)__popcll(mask & ((1ull << (t & 63)) - 1ull));
      nzidx[pos] = t;
    }
  }
  __syncthreads();
  const int nz = woff[6];

  // ---- M2 (sparse k): feat = relu(hmid @ W2 + b2), 16 k-slices -------------
  {
    const int jg = t & 63, ks = t >> 6;
    const int j0 = jg << 2;
    float4 acc = make_float4(0.f, 0.f, 0.f, 0.f);
    for (int i = ks; i < nz; i += 16) {
      const int k = nzidx[i];
      const float4 wt = *(const float4*)(W2 + (size_t)k * 256 + j0);
      const float xk = hmid[k];
      acc.x += xk * wt.x; acc.y += xk * wt.y;
      acc.z += xk * wt.z; acc.w += xk * wt.w;
    }
    zacc[t] = acc;
  }
  __syncthreads();
  if (t < 64) {
    float4 a = zacc[t];
#pragma unroll
    for (int sl = 1; sl < 16; ++sl) {
      const float4 bq = zacc[sl * 64 + t];
      a.x += bq.x; a.y += bq.y; a.z += bq.z; a.w += bq.w;
    }
    const float4 bb = *(const float4*)(b2 + (t << 2));
    float4 fv;
    fv.x = fmaxf(a.x + bb.x, 0.f);
    fv.y = fmaxf(a.y + bb.y, 0.f);
    fv.z = fmaxf(a.z + bb.z, 0.f);
    fv.w = fmaxf(a.w + bb.w, 0.f);
    ((float4*)(featb + (size_t)w * 256))[t] = fv;
  }
}

// ---------------------------------------------------------------------------
// kB: gather-bound scoring, 4 threads/candidate. grid = 512 x 512. (R11)
// ---------------------------------------------------------------------------
__global__ __launch_bounds__(512) void kB(
    int step,
    const float* __restrict__ ent_emb, const float* __restrict__ rel_emb,
    const int* __restrict__ cand_rel_ids, const int* __restrict__ cand_ent_ids,
    const float* __restrict__ featb, float* __restrict__ scoresb)
{
  const int b = blockIdx.x, tid = threadIdx.x;
  const int w = b >> 3, c0 = (b & 7) << 7;
  __shared__ __align__(16) float featl[256];
  __shared__ int srid[128], seid[128];

  const size_t idbase = (size_t)step * W * C + (size_t)w * C + c0;
  if (tid < 256) featl[tid] = featb[(size_t)w * 256 + tid];
  else if (tid < 384) srid[tid - 256] = cand_rel_ids[idbase + (tid - 256)];
  else seid[tid - 384] = cand_ent_ids[idbase + (tid - 384)];
  __syncthreads();

  const int cl = tid >> 2, j = tid & 3;
  const float4* rp = (const float4*)(rel_emb + (size_t)srid[cl] * E);
  const float4* ep = (const float4*)(ent_emb + (size_t)seid[cl] * E);
  const float4* f4 = (const float4*)featl;
  float ax = 0.f, ay = 0.f, az = 0.f, aw = 0.f;
#pragma unroll
  for (int i = 0; i < 8; ++i) {
    const float4 r = rp[j + 4 * i], f = f4[j + 4 * i];
    ax += r.x * f.x; ay += r.y * f.y; az += r.z * f.z; aw += r.w * f.w;
  }
#pragma unroll
  for (int i = 0; i < 8; ++i) {
    const float4 e = ep[j + 4 * i], f = f4[32 + j + 4 * i];
    ax += e.x * f.x; ay += e.y * f.y; az += e.z * f.z; aw += e.w * f.w;
  }
  float acc = (ax + ay) + (az + aw);
  acc += __shfl_xor(acc, 1, 64);
  acc += __shfl_xor(acc, 2, 64);
  if (j == 0) scoresb[(size_t)w * C + c0 + cl] = acc;
}

// ---------------------------------------------------------------------------
// kC: softmax -> out, per-row top-64 -> rowtop. grid = 64 x 1024. (R11)
// ---------------------------------------------------------------------------
__global__ __launch_bounds__(1024) void kC(
    int step, int last, const float* __restrict__ scoresb,
    float* __restrict__ out, u64* __restrict__ rowtop)
{
  const int w = blockIdx.x, t = threadIdx.x;
  const int lane = t & 63, wid = t >> 6;
  __shared__ float sred[16];
  __shared__ float s_m, s_inv;
  __shared__ u32 wtot[16];
  __shared__ int s_cnt, s_B;
  __shared__ __align__(16) unsigned char arena[32768];
  u32* hist = (u32*)arena;
  u64* coll = (u64*)arena;

  const float score = scoresb[(size_t)w * C + t];

  float v = score;
#pragma unroll
  for (int d = 32; d; d >>= 1) v = fmaxf(v, __shfl_xor(v, d, 64));
  if (lane == 0) sred[wid] = v;
  __syncthreads();
  if (t == 0) {
    float mm = sred[0];
#pragma unroll
    for (int i = 1; i < 16; ++i) mm = fmaxf(mm, sred[i]);
    s_m = mm;
  }
  __syncthreads();
  const float pexp = expf(score - s_m);
  v = pexp;
#pragma unroll
  for (int d = 32; d; d >>= 1) v += __shfl_xor(v, d, 64);
  if (lane == 0) sred[wid] = v;
  __syncthreads();
  if (t == 0) {
    float ss = sred[0];
#pragma unroll
    for (int i = 1; i < 16; ++i) ss += sred[i];
    s_inv = 1.f / ss;
  }
  __syncthreads();
  const float prob = pexp * s_inv;
  out[(size_t)step * W * C + (size_t)w * C + t] = prob;

  if (!last) {
    ((uint4*)hist)[t] = make_uint4(0u, 0u, 0u, 0u);
    if (t == 0) s_cnt = 0;
    __syncthreads();
    const u32 mono = __float_as_uint(prob) | 0x80000000u;
    const u64 key = ((u64)mono << 32) | (u32)~(u32)(w * C + t);
    atomicAdd(&hist[(mono >> 19) & 0xFFFu], 1u);
    __syncthreads();
    const int B = suffix_threshold(hist, wtot, &s_B, t, lane, wid);
    if ((int)((mono >> 19) & 0xFFFu) >= B) coll[atomicAdd(&s_cnt, 1)] = key;
    __syncthreads();
    const int M = s_cnt;
    for (int i = t; i < M; i += 1024) {
      const u64 ki = coll[i];
      int r = 0;
      for (int j = 0; j < M; ++j) r += (coll[j] > ki);
      if (r < 64) rowtop[(size_t)w * 64 + r] = ki;
    }
  }
}

// ---------------------------------------------------------------------------
extern "C" void kernel_launch(void* const* d_in, const int* in_sizes, int n_in,
                              void* d_out, int out_size, void* d_ws, size_t ws_size,
                              hipStream_t stream) {
  const float* ent_emb  = (const float*)d_in[0];
  const float* rel_emb  = (const float*)d_in[1];
  const float* relation = (const float*)d_in[2];
  const float* W1 = (const float*)d_in[3];
  const float* b1 = (const float*)d_in[4];
  const float* W2 = (const float*)d_in[5];
  const float* b2 = (const float*)d_in[6];
  const float* lstm_k = (const float*)d_in[7];
  const float* lstm_r = (const float*)d_in[8];
  const float* lstm_b = (const float*)d_in[9];
  const int* cr = (const int*)d_in[10];
  const int* ce = (const int*)d_in[11];
  const int* start_ent = (const int*)d_in[12];
  float* out = (float*)d_out;

  u64* rowtop = (u64*)d_ws;                                 // W*64 u64
  float* Hst = (float*)(rowtop + (size_t)W * 64);           // 2*W*E
  float* Cst = Hst + (size_t)2 * W * E;                     // 2*W*E
  float* rconstb = Cst + (size_t)2 * W * E;                 // 384
  float* featb = rconstb + 384;                             // W*256
  float* scoresb = featb + (size_t)W * 256;                 // W*C
  float* relz = scoresb + (size_t)W * C;                    // 1000*512

  kRelz<<<250, 1024, 0, stream>>>(rel_emb, lstm_k, relz);
  for (int s = 0; s < S; ++s) {
    kA<<<W, 1024, 0, stream>>>(s, ent_emb, rel_emb, relation, W1, b1, W2, b2,
                               lstm_k, lstm_r, lstm_b, relz, cr, ce, start_ent,
                               Hst, Cst, rconstb, rowtop, featb);
    kB<<<512, 512, 0, stream>>>(s, ent_emb, rel_emb, cr, ce, featb, scoresb);
    kC<<<W, 1024, 0, stream>>>(s, (s == S - 1) ? 1 : 0, scoresb, out, rowtop);
  }
}